// Round 13
// baseline (499.066 us; speedup 1.0000x reference)
//
#include <hip/hip_runtime.h>
#include <math.h>

typedef unsigned short ushortT;
typedef __attribute__((ext_vector_type(8))) short short8;
typedef __attribute__((ext_vector_type(4))) float f32x4;

#define NN 4096
#define DD 1024
#define NC 100
#define NLAB 2048
#define NITER 30
#define XPBUF 262144  // ushorts per X^T buffer (0.5 MB)

__device__ __forceinline__ ushortT bf16rn(float x) {
  unsigned u = __float_as_uint(x);
  unsigned r = (u + 0x7fffu + ((u >> 16) & 1u)) >> 16;
  return (ushortT)r;
}
__device__ __forceinline__ float bf2f(ushortT h) {
  return __uint_as_float(((unsigned)h) << 16);
}
__device__ __forceinline__ void gload16(const void* g, void* l) {
  __builtin_amdgcn_global_load_lds((const __attribute__((address_space(1))) char*)g,
                                   (__attribute__((address_space(3))) char*)l, 16, 0, 0);
}

// ---------------- normalize rows -> bf16 ----------------
__global__ __launch_bounds__(256) void k_normalize(const float* __restrict__ E,
                                                   ushortT* __restrict__ Enh) {
  int row = blockIdx.x, t = threadIdx.x;
  const float4* e4 = (const float4*)(E + (size_t)row * DD);
  float4 v = e4[t];
  float ss = v.x * v.x + v.y * v.y + v.z * v.z + v.w * v.w;
  __shared__ float red[4];
  int lane = t & 63, w = t >> 6;
#pragma unroll
  for (int off = 32; off; off >>= 1) ss += __shfl_xor(ss, off);
  if (lane == 0) red[w] = ss;
  __syncthreads();
  float tot = red[0] + red[1] + red[2] + red[3];
  float d = fmaxf(sqrtf(tot), 1e-12f);
  ushort4 hv;
  hv.x = bf16rn(v.x / d); hv.y = bf16rn(v.y / d);
  hv.z = bf16rn(v.z / d); hv.w = bf16rn(v.w / d);
  ((ushort4*)Enh)[(size_t)row * 256 + t] = hv;
}

// ---------------- A0 = relu(En@En^T) pure bf16; diag=1; A stored bf16 ----------------
__global__ __launch_bounds__(256, 4) void k_syrk_mfma(const ushortT* __restrict__ Enh,
                                                      ushortT* __restrict__ A) {
  int xg = (int)blockIdx.x & 7;
  int j = (int)blockIdx.x >> 3;  // 0..79
  int bi = -1, bj = 0;
#pragma unroll
  for (int p = 0; p < 4; ++p) {
    int bic = xg + (p << 3);
    int c = 32 - bic;
    if (bi < 0) {
      if (j < c) { bi = bic; bj = bic + j; } else j -= c;
    }
  }
  if (bi < 0) return;
  __shared__ ushortT lds[18432];
  int t = threadIdx.x;
  int l = t & 63, w = t >> 6;
  int i0 = bi << 7, j0 = bj << 7;
  int wr = w >> 1, wc = w & 1;
  f32x4 zz = {0.f, 0.f, 0.f, 0.f};
  f32x4 acc[4][4];
#pragma unroll
  for (int m = 0; m < 4; ++m)
#pragma unroll
    for (int n = 0; n < 4; ++n) acc[m][n] = zz;
  int arow_l = l & 15, kslot = l >> 4;

  for (int s = 0; s < 16; ++s) {
    int kk0 = s << 6;
#pragma unroll
    for (int q = 0; q < 4; ++q) {
      int n = (q << 8) + t;
      int r = n >> 3, p = n & 7;
      int col = (p ^ (r & 7)) << 3;
      gload16(Enh + (size_t)(i0 + r) * DD + kk0 + col, &lds[n << 3]);
      gload16(Enh + (size_t)(j0 + r) * DD + kk0 + col, &lds[8192 + (n << 3)]);
    }
    __syncthreads();
#pragma unroll
    for (int kk = 0; kk < 2; ++kk) {
      int g = (kk << 2) + kslot;
      short8 av[4], bv[4];
#pragma unroll
      for (int m = 0; m < 4; ++m) {
        int r = (wr << 6) + (m << 4) + arow_l;
        av[m] = *(const short8*)&lds[(r << 6) + ((g ^ (r & 7)) << 3)];
      }
#pragma unroll
      for (int n = 0; n < 4; ++n) {
        int r = (wc << 6) + (n << 4) + arow_l;
        bv[n] = *(const short8*)&lds[8192 + (r << 6) + ((g ^ (r & 7)) << 3)];
      }
#pragma unroll
      for (int m = 0; m < 4; ++m)
#pragma unroll
        for (int n = 0; n < 4; ++n)
          acc[m][n] = __builtin_amdgcn_mfma_f32_16x16x32_bf16(av[m], bv[n], acc[m][n], 0, 0, 0);
    }
    __syncthreads();
  }
  int rbase = (l >> 4) << 2;
#pragma unroll
  for (int m = 0; m < 4; ++m) {
#pragma unroll
    for (int n = 0; n < 4; ++n) {
#pragma unroll
      for (int r = 0; r < 4; ++r) {
        int gi = i0 + (wr << 6) + (m << 4) + rbase + r;
        int gj = j0 + (wc << 6) + (n << 4) + (l & 15);
        float v = fmaxf(acc[m][n][r], 0.0f);
        if (gi == gj) v = 1.0f;
        A[(size_t)gi * NN + gj] = bf16rn(v);
      }
    }
  }
  if (bi != bj) {
    float* T = (float*)&lds[0];
#pragma unroll
    for (int c2 = 0; c2 < 2; ++c2) {
      __syncthreads();
      if (wr == c2) {
#pragma unroll
        for (int m = 0; m < 4; ++m)
#pragma unroll
          for (int n = 0; n < 4; ++n)
#pragma unroll
            for (int r = 0; r < 4; ++r)
              T[(((wc << 6) + (n << 4) + (l & 15)) * 68) + (m << 4) + rbase + r] =
                  fmaxf(acc[m][n][r], 0.0f);
      }
      __syncthreads();
      int lj = t >> 1, cg = (t & 1) << 5;
#pragma unroll
      for (int q = 0; q < 4; ++q) {
        float4 a0 = *(const float4*)&T[lj * 68 + cg + (q << 3)];
        float4 a1 = *(const float4*)&T[lj * 68 + cg + (q << 3) + 4];
        short8 o;
        o[0] = (short)bf16rn(a0.x); o[1] = (short)bf16rn(a0.y);
        o[2] = (short)bf16rn(a0.z); o[3] = (short)bf16rn(a0.w);
        o[4] = (short)bf16rn(a1.x); o[5] = (short)bf16rn(a1.y);
        o[6] = (short)bf16rn(a1.z); o[7] = (short)bf16rn(a1.w);
        *(short8*)&A[(size_t)(j0 + lj) * NN + i0 + (c2 << 6) + cg + (q << 3)] = o;
      }
    }
  }
}

// ---------------- sigma[i] = 7th largest of row i (bf16 A) ----------------
__device__ __forceinline__ void ins7(float (&tv)[7], float v) {
  if (v > tv[6]) {
#pragma unroll
    for (int s = 0; s < 7; s++) {
      if (v > tv[s]) { float tmp = tv[s]; tv[s] = v; v = tmp; }
    }
  }
}
__global__ __launch_bounds__(256) void k_top7(const ushortT* __restrict__ A,
                                              float* __restrict__ sig) {
  int w = threadIdx.x >> 6, lane = threadIdx.x & 63;
  int row = (blockIdx.x << 2) + w;
  const ushortT* a = A + (size_t)row * NN;
  float tv[7];
#pragma unroll
  for (int i = 0; i < 7; i++) tv[i] = -1.0f;
#pragma unroll
  for (int k = 0; k < 8; k++) {
    short8 v = *(const short8*)(a + (k << 9) + (lane << 3));
#pragma unroll
    for (int jj = 0; jj < 8; jj++) ins7(tv, bf2f((ushortT)v[jj]));
  }
  int head = 0;
  float seventh = 0.0f;
  for (int r = 0; r < 7; r++) {
    float h = (head < 7) ? tv[head] : -1.0f;
    float m = h;
#pragma unroll
    for (int off = 32; off; off >>= 1) m = fmaxf(m, __shfl_xor(m, off));
    unsigned long long ball = __ballot(h == m);
    if (lane == (__ffsll(ball) - 1)) head++;
    seventh = m;
  }
  if (lane == 0) sig[row] = seventh;
}

// ---------------- mean pass over bf16 A ----------------
__global__ __launch_bounds__(256) void k_transform(const ushortT* __restrict__ A,
                                                   const float* __restrict__ sig,
                                                   double* __restrict__ parts) {
  int row = blockIdx.x;
  float si = sig[row];
  const ushortT* a = A + (size_t)row * NN;
  int t = threadIdx.x;
  double local = 0.0;
#pragma unroll
  for (int k = 0; k < 2; k++) {
    int idx = (k << 11) + (t << 3);
    short8 v = *(const short8*)(a + idx);
#pragma unroll
    for (int q = 0; q < 2; ++q) {
      float4 sg = *(const float4*)&sig[idx + (q << 2)];
      float s0 = bf2f((ushortT)v[(q << 2) + 0]);
      float s1 = bf2f((ushortT)v[(q << 2) + 1]);
      float s2 = bf2f((ushortT)v[(q << 2) + 2]);
      float s3 = bf2f((ushortT)v[(q << 2) + 3]);
      local += (double)expf(-(s0 * s0) / (si * sg.x)) +
               (double)expf(-(s1 * s1) / (si * sg.y)) +
               (double)expf(-(s2 * s2) / (si * sg.z)) +
               (double)expf(-(s3 * s3) / (si * sg.w));
    }
  }
  __shared__ double dred[4];
  int lane = t & 63, wv = t >> 6;
#pragma unroll
  for (int off = 32; off; off >>= 1) local += __shfl_xor(local, off);
  if (lane == 0) dred[wv] = local;
  __syncthreads();
  if (t == 0) parts[row] = dred[0] + dred[1] + dred[2] + dred[3];
}

__global__ __launch_bounds__(256) void k_mean(const double* __restrict__ parts,
                                              float* __restrict__ meanb) {
  int t = threadIdx.x;
  double local = 0.0;
#pragma unroll
  for (int k = 0; k < NN / 256; k++) local += parts[(k << 8) + t];
  __shared__ double dred[4];
  int lane = t & 63, wv = t >> 6;
#pragma unroll
  for (int off = 32; off; off >>= 1) local += __shfl_xor(local, off);
  if (lane == 0) dred[wv] = local;
  __syncthreads();
  if (t == 0) meanb[0] = (float)((dred[0] + dred[1] + dred[2] + dred[3]) / ((double)NN * (double)NN));
}

// ---------------- thresh: exp on bottom half (bf16 A), threshold, pack ----------------
__global__ __launch_bounds__(256) void k_thresh_pack(const ushortT* __restrict__ A,
                                                     const float* __restrict__ sig,
                                                     const float* __restrict__ meanb,
                                                     ushortT* __restrict__ ApL,
                                                     ushortT* __restrict__ ApU) {
  float m = meanb[0];
  int i8 = ((int)blockIdx.x << 8) + threadIdx.x;  // 1M over [2048][512 groups of 8]
  int row2 = i8 >> 9;
  int col8 = (i8 & 511) << 3;
  int grow = NLAB + row2;
  float si = sig[grow];
  short8 v = *(const short8*)&A[(size_t)grow * NN + col8];
  short8 o;
#pragma unroll
  for (int q = 0; q < 2; ++q) {
    float4 sg = *(const float4*)&sig[col8 + (q << 2)];
    float s0 = bf2f((ushortT)v[(q << 2) + 0]);
    float s1 = bf2f((ushortT)v[(q << 2) + 1]);
    float s2 = bf2f((ushortT)v[(q << 2) + 2]);
    float s3 = bf2f((ushortT)v[(q << 2) + 3]);
    float c0 = expf(-(s0 * s0) / (si * sg.x));
    float c1 = expf(-(s1 * s1) / (si * sg.y));
    float c2 = expf(-(s2 * s2) / (si * sg.z));
    float c3 = expf(-(s3 * s3) / (si * sg.w));
    o[(q << 2) + 0] = (short)((c0 < m) ? 0 : bf16rn(c0));
    o[(q << 2) + 1] = (short)((c1 < m) ? 0 : bf16rn(c1));
    o[(q << 2) + 2] = (short)((c2 < m) ? 0 : bf16rn(c2));
    o[(q << 2) + 3] = (short)((c3 < m) ? 0 : bf16rn(c3));
  }
  int half = col8 >> 11;
  int cc = col8 & 2047;
  int rt = row2 >> 4, arow = row2 & 15;
  int kc = cc >> 5, khi = (cc >> 3) & 3;
  ushortT* dst = half ? ApU : ApL;
  *(short8*)&dst[((size_t)((rt << 6) + kc) << 9) + (khi << 7) + (arow << 3)] = o;
}

// ---------------- one-hot labels, packed layout ----------------
__global__ __launch_bounds__(256) void k_xlabp(const int* __restrict__ labels,
                                               ushortT* __restrict__ Xlabp) {
  int idx = ((int)blockIdx.x << 8) + threadIdx.x;  // 262144
  int c = idx >> 11, j = idx & 2047;
  int kc = j >> 5, khi = (j >> 3) & 3, k0 = j & 7;
  int cf = c >> 4, slot = c & 15;
  Xlabp[((size_t)(((kc << 3) + cf) << 2) + khi) * 128 + (slot << 3) + k0] =
      (labels[j] == c) ? (ushortT)0x3F80 : (ushortT)0;
}

// ---------------- X init: packed X^T buffer 0 ----------------
__global__ __launch_bounds__(64) void k_xinit(ushortT* __restrict__ Xp) {
  int rt = blockIdx.x, l = threadIdx.x;
  int col = l & 15, rg4 = l >> 4;
  int kc = rt >> 1;
  int kk = ((rt & 1) << 4) + (rg4 << 2);
  int khi = kk >> 3, k0 = kk & 7;
#pragma unroll
  for (int cf = 0; cf < 8; ++cf) {
    int cls = (cf << 4) + col;
    float v = (cls < NC) ? 0.01f : 0.0f;
    ushortT h = bf16rn(v);
    ushort4 hv = {h, h, h, h};
    *(ushort4*)&Xp[((size_t)(((kc << 3) + cf) << 2) + khi) * 128 + (col << 3) + k0] = hv;
  }
}

// ---------------- persistent iteration kernel: all 30 iterations in one launch ------
// 256 blocks x 256 thr (all co-resident). Block = (rt 16 rows) x (cf half).
// Ylab + x in registers. X^T exchanged via fresh per-iteration buffers written with
// device-scope atomic exchange (L2-bypassing) -> no L2 invalidation ever; A stays hot.
__global__ __launch_bounds__(256) void k_persist(
    const ushortT* __restrict__ ApL, const ushortT* __restrict__ ApU,
    const ushortT* __restrict__ Xlabp, ushortT* __restrict__ XpBase,
    float* __restrict__ Xf, float* __restrict__ sums2, int* __restrict__ cnt2,
    int* __restrict__ gbar) {
  __shared__ float red[4][4][64][4];  // 16 KB
  __shared__ float sums_l[4][16];
  __shared__ float totl[16];
  int t = threadIdx.x, l = t & 63, w = t >> 6;
  int bid = (int)blockIdx.x;
  int rt = ((bid & 7) << 4) + ((bid >> 3) & 15);
  int half = bid >> 7;
  int cf = (half << 2) + w;
  int rg4 = l >> 4, col16 = l & 15;

  auto gemm = [&](const ushortT* __restrict__ Ap, const ushortT* __restrict__ Xp) -> f32x4 {
    __syncthreads();  // protect red reuse
    const ushortT* ab = Ap + ((size_t)rt << 15) + ((size_t)(w << 4) << 9) + (l << 3);
    const ushortT* xb = Xp + ((size_t)(w << 4) << 12) + ((size_t)(half << 2) << 9) + (l << 3);
    f32x4 acc[4];
#pragma unroll
    for (int cc = 0; cc < 4; ++cc) acc[cc] = (f32x4){0.f, 0.f, 0.f, 0.f};
#pragma unroll
    for (int i = 0; i < 16; ++i) {
      short8 av = *(const short8*)(ab + ((size_t)i << 9));
#pragma unroll
      for (int cc = 0; cc < 4; ++cc) {
        short8 bv = *(const short8*)(xb + ((size_t)i << 12) + (cc << 9));
        acc[cc] = __builtin_amdgcn_mfma_f32_16x16x32_bf16(av, bv, acc[cc], 0, 0, 0);
      }
    }
#pragma unroll
    for (int cc = 0; cc < 4; ++cc) *(f32x4*)&red[w][cc][l][0] = acc[cc];
    __syncthreads();
    f32x4 mm = (f32x4){0.f, 0.f, 0.f, 0.f};
#pragma unroll
    for (int wp = 0; wp < 4; ++wp) {
      f32x4 p = *(const f32x4*)&red[wp][w][l][0];
      mm[0] += p[0]; mm[1] += p[1]; mm[2] += p[2]; mm[3] += p[3];
    }
    return mm;
  };

  // Ylab (constant) into registers
  f32x4 yl = gemm(ApL, Xlabp);
  // x init
  f32x4 x;
  {
    float v = ((cf << 4) + col16 < NC) ? 0.01f : 0.0f;
    x[0] = v; x[1] = v; x[2] = v; x[3] = v;
  }

  for (int it = 0; it < NITER; ++it) {
    f32x4 mm = gemm(ApU, XpBase + (size_t)it * XPBUF);
    f32x4 mult, rs;
#pragma unroll
    for (int r = 0; r < 4; ++r) {
      mult[r] = fmaf(x[r], mm[r] + yl[r], x[r]);
      rs[r] = mult[r];
    }
#pragma unroll
    for (int msk = 1; msk < 16; msk <<= 1) {
#pragma unroll
      for (int r = 0; r < 4; ++r) rs[r] += __shfl_xor(rs[r], msk);
    }
    if (col16 == 0) {
#pragma unroll
      for (int r = 0; r < 4; ++r) sums_l[w][(rg4 << 2) + r] = rs[r];
    }
    __syncthreads();
    float* s2 = sums2 + ((size_t)it << 11);
    int* c2 = cnt2 + (it << 7);
    if (w == 0 && l < 16) {
      float hs = sums_l[0][l] + sums_l[1][l] + sums_l[2][l] + sums_l[3][l];
      atomicAdd(&s2[(rt << 4) + l], hs);
    }
    if (t == 0) {
      asm volatile("s_waitcnt vmcnt(0)" ::: "memory");
      atomicAdd(&c2[rt], 1);
      while (atomicAdd(&c2[rt], 0) < 2) __builtin_amdgcn_s_sleep(1);
    }
    __syncthreads();
    if (w == 0 && l < 16) totl[l] = atomicAdd(&s2[(rt << 4) + l], 0.0f) + 1e-8f;
    __syncthreads();
#pragma unroll
    for (int r = 0; r < 4; ++r) x[r] = mult[r] / totl[(rg4 << 2) + r];

    if (it < NITER - 1) {
      // publish X^T(it+1) via device-scope atomic exchange (L2-bypass)
      ushortT* Xn = XpBase + (size_t)(it + 1) * XPBUF;
      int kcp = rt >> 1;
      int rem = ((rt & 1) << 4) + (rg4 << 2);
      int khi = rem >> 3, k0 = rem & 7;
      unsigned long long pk =
          (unsigned long long)bf16rn(x[0]) |
          ((unsigned long long)bf16rn(x[1]) << 16) |
          ((unsigned long long)bf16rn(x[2]) << 32) |
          ((unsigned long long)bf16rn(x[3]) << 48);
      size_t off = ((size_t)(((kcp << 3) + cf) << 2) + khi) * 128 + (col16 << 3) + k0;
      __hip_atomic_exchange((unsigned long long*)&Xn[off], pk, __ATOMIC_RELAXED,
                            __HIP_MEMORY_SCOPE_AGENT);
      asm volatile("s_waitcnt vmcnt(0)" ::: "memory");
      __syncthreads();
      // hierarchical grid barrier on fresh per-iteration counters
      if (t == 0) {
        int* ga = gbar + it * 17;
        int grp = bid >> 5;
        int a = __hip_atomic_fetch_add(&ga[grp], 1, __ATOMIC_RELAXED,
                                       __HIP_MEMORY_SCOPE_AGENT);
        if (a == 31) {
          int g2 = __hip_atomic_fetch_add(&ga[8], 1, __ATOMIC_RELAXED,
                                          __HIP_MEMORY_SCOPE_AGENT);
          if (g2 == 7) {
#pragma unroll
            for (int q = 0; q < 8; ++q)
              __hip_atomic_fetch_add(&ga[9 + q], 1, __ATOMIC_RELAXED,
                                     __HIP_MEMORY_SCOPE_AGENT);
          } else {
            while (__hip_atomic_fetch_add(&ga[9 + grp], 0, __ATOMIC_RELAXED,
                                          __HIP_MEMORY_SCOPE_AGENT) == 0)
              __builtin_amdgcn_s_sleep(1);
          }
        } else {
          while (__hip_atomic_fetch_add(&ga[9 + grp], 0, __ATOMIC_RELAXED,
                                        __HIP_MEMORY_SCOPE_AGENT) == 0)
            __builtin_amdgcn_s_sleep(1);
        }
      }
      __syncthreads();
    }
  }
  // final X (frag-major f32) for k_output
  size_t fo = (size_t)((rt << 3) + cf) * 64 + l;
  ((f32x4*)Xf)[fo] = x;
}

// ---------------- output assembly ----------------
__global__ __launch_bounds__(256) void k_output(const float* __restrict__ Xf,
                                                const int* __restrict__ labels,
                                                float* __restrict__ out) {
  int idx = ((int)blockIdx.x << 8) + threadIdx.x;  // 409600
  int i = idx / NC, c = idx - i * NC;
  float v;
  if (i < NLAB) {
    v = (labels[i] == c) ? 1.0f : 0.0f;
  } else {
    int row = i - NLAB;
    int rt = row >> 4, r = row & 15;
    int rg4 = r >> 2, reg = r & 3;
    int cf = c >> 4, col = c & 15;
    v = Xf[((size_t)(((rt << 3) + cf) << 6) + (rg4 << 4) + col) * 4 + reg];
  }
  out[idx] = v;
}

extern "C" void kernel_launch(void* const* d_in, const int* in_sizes, int n_in,
                              void* d_out, int out_size, void* d_ws, size_t ws_size,
                              hipStream_t stream) {
  const float* E = (const float*)d_in[0];
  const int* labels = (const int*)d_in[1];
  float* out = (float*)d_out;
  char* ws = (char*)d_ws;
  const size_t MB = 1024 * 1024;

  ushortT* A = (ushortT*)ws;                      // 32 MB bf16
  ushortT* Enh = (ushortT*)(ws + 32 * MB);        // 8 MB
  ushortT* ApL = (ushortT*)(ws + 40 * MB);        // 8 MB packed A[:, :2048]
  ushortT* ApU = (ushortT*)(ws + 48 * MB);        // 8 MB packed A[:, 2048:]
  float* sig = (float*)(ws + 56 * MB);
  double* parts = (double*)(ws + 56 * MB + 65536);
  float* meanb = (float*)(ws + 56 * MB + 131072);
  ushortT* Xlabp = (ushortT*)(ws + 57 * MB);      // 0.5 MB packed
  float* Xf = (float*)(ws + 58 * MB);             // 1 MB final X (frag-major)
  ushortT* XpBase = (ushortT*)(ws + 64 * MB);     // 30 x 0.5 MB fresh X^T buffers
  float* sums2 = (float*)(ws + 80 * MB);          // 240 KB
  int* cnt2 = (int*)(ws + 81 * MB);               // 15 KB
  int* gbar = (int*)(ws + 82 * MB);               // 30*17 ints

  k_normalize<<<NN, 256, 0, stream>>>(E, Enh);
  k_syrk_mfma<<<640, 256, 0, stream>>>(Enh, A);
  k_top7<<<NN / 4, 256, 0, stream>>>(A, sig);
  k_transform<<<NN, 256, 0, stream>>>(A, sig, parts);
  k_mean<<<1, 256, 0, stream>>>(parts, meanb);
  k_thresh_pack<<<4096, 256, 0, stream>>>(A, sig, meanb, ApL, ApU);
  k_xlabp<<<1024, 256, 0, stream>>>(labels, Xlabp);
  k_xinit<<<128, 64, 0, stream>>>(XpBase);
  hipMemsetAsync(sums2, 0, (size_t)NITER * 2048 * sizeof(float), stream);
  hipMemsetAsync(cnt2, 0, (size_t)NITER * 128 * sizeof(int), stream);
  hipMemsetAsync(gbar, 0, (size_t)NITER * 17 * sizeof(int), stream);
  k_persist<<<256, 256, 0, stream>>>(ApL, ApU, Xlabp, XpBase, Xf, sums2, cnt2, gbar);
  k_output<<<1600, 256, 0, stream>>>(Xf, labels, out);
}

// Round 14
// 421.643 us; speedup vs baseline: 1.1836x; 1.1836x over previous
//
#include <hip/hip_runtime.h>
#include <math.h>

typedef unsigned short ushortT;
typedef __attribute__((ext_vector_type(8))) short short8;
typedef __attribute__((ext_vector_type(4))) float f32x4;

#define NN 4096
#define DD 1024
#define NC 100
#define NLAB 2048
#define NITER 30

__device__ __forceinline__ ushortT bf16rn(float x) {
  unsigned u = __float_as_uint(x);
  unsigned r = (u + 0x7fffu + ((u >> 16) & 1u)) >> 16;
  return (ushortT)r;
}
__device__ __forceinline__ float bf2f(ushortT h) {
  return __uint_as_float(((unsigned)h) << 16);
}
__device__ __forceinline__ void gload16(const void* g, void* l) {
  __builtin_amdgcn_global_load_lds((const __attribute__((address_space(1))) char*)g,
                                   (__attribute__((address_space(3))) char*)l, 16, 0, 0);
}

// ---------------- normalize rows -> bf16 ----------------
__global__ __launch_bounds__(256) void k_normalize(const float* __restrict__ E,
                                                   ushortT* __restrict__ Enh) {
  int row = blockIdx.x, t = threadIdx.x;
  const float4* e4 = (const float4*)(E + (size_t)row * DD);
  float4 v = e4[t];
  float ss = v.x * v.x + v.y * v.y + v.z * v.z + v.w * v.w;
  __shared__ float red[4];
  int lane = t & 63, w = t >> 6;
#pragma unroll
  for (int off = 32; off; off >>= 1) ss += __shfl_xor(ss, off);
  if (lane == 0) red[w] = ss;
  __syncthreads();
  float tot = red[0] + red[1] + red[2] + red[3];
  float d = fmaxf(sqrtf(tot), 1e-12f);
  ushort4 hv;
  hv.x = bf16rn(v.x / d); hv.y = bf16rn(v.y / d);
  hv.z = bf16rn(v.z / d); hv.w = bf16rn(v.w / d);
  ((ushort4*)Enh)[(size_t)row * 256 + t] = hv;
}

// ---------------- A0 = relu(En@En^T) pure bf16; diag=1; A stored bf16 ----------------
__global__ __launch_bounds__(256, 4) void k_syrk_mfma(const ushortT* __restrict__ Enh,
                                                      ushortT* __restrict__ A) {
  int xg = (int)blockIdx.x & 7;
  int j = (int)blockIdx.x >> 3;  // 0..79
  int bi = -1, bj = 0;
#pragma unroll
  for (int p = 0; p < 4; ++p) {
    int bic = xg + (p << 3);
    int c = 32 - bic;
    if (bi < 0) {
      if (j < c) { bi = bic; bj = bic + j; } else j -= c;
    }
  }
  if (bi < 0) return;
  __shared__ ushortT lds[18432];
  int t = threadIdx.x;
  int l = t & 63, w = t >> 6;
  int i0 = bi << 7, j0 = bj << 7;
  int wr = w >> 1, wc = w & 1;
  f32x4 zz = {0.f, 0.f, 0.f, 0.f};
  f32x4 acc[4][4];
#pragma unroll
  for (int m = 0; m < 4; ++m)
#pragma unroll
    for (int n = 0; n < 4; ++n) acc[m][n] = zz;
  int arow_l = l & 15, kslot = l >> 4;

  for (int s = 0; s < 16; ++s) {
    int kk0 = s << 6;
#pragma unroll
    for (int q = 0; q < 4; ++q) {
      int n = (q << 8) + t;
      int r = n >> 3, p = n & 7;
      int col = (p ^ (r & 7)) << 3;
      gload16(Enh + (size_t)(i0 + r) * DD + kk0 + col, &lds[n << 3]);
      gload16(Enh + (size_t)(j0 + r) * DD + kk0 + col, &lds[8192 + (n << 3)]);
    }
    __syncthreads();
#pragma unroll
    for (int kk = 0; kk < 2; ++kk) {
      int g = (kk << 2) + kslot;
      short8 av[4], bv[4];
#pragma unroll
      for (int m = 0; m < 4; ++m) {
        int r = (wr << 6) + (m << 4) + arow_l;
        av[m] = *(const short8*)&lds[(r << 6) + ((g ^ (r & 7)) << 3)];
      }
#pragma unroll
      for (int n = 0; n < 4; ++n) {
        int r = (wc << 6) + (n << 4) + arow_l;
        bv[n] = *(const short8*)&lds[8192 + (r << 6) + ((g ^ (r & 7)) << 3)];
      }
#pragma unroll
      for (int m = 0; m < 4; ++m)
#pragma unroll
        for (int n = 0; n < 4; ++n)
          acc[m][n] = __builtin_amdgcn_mfma_f32_16x16x32_bf16(av[m], bv[n], acc[m][n], 0, 0, 0);
    }
    __syncthreads();
  }
  int rbase = (l >> 4) << 2;
#pragma unroll
  for (int m = 0; m < 4; ++m) {
#pragma unroll
    for (int n = 0; n < 4; ++n) {
#pragma unroll
      for (int r = 0; r < 4; ++r) {
        int gi = i0 + (wr << 6) + (m << 4) + rbase + r;
        int gj = j0 + (wc << 6) + (n << 4) + (l & 15);
        float v = fmaxf(acc[m][n][r], 0.0f);
        if (gi == gj) v = 1.0f;
        A[(size_t)gi * NN + gj] = bf16rn(v);
      }
    }
  }
  if (bi != bj) {
    float* T = (float*)&lds[0];
#pragma unroll
    for (int c2 = 0; c2 < 2; ++c2) {
      __syncthreads();
      if (wr == c2) {
#pragma unroll
        for (int m = 0; m < 4; ++m)
#pragma unroll
          for (int n = 0; n < 4; ++n)
#pragma unroll
            for (int r = 0; r < 4; ++r)
              T[(((wc << 6) + (n << 4) + (l & 15)) * 68) + (m << 4) + rbase + r] =
                  fmaxf(acc[m][n][r], 0.0f);
      }
      __syncthreads();
      int lj = t >> 1, cg = (t & 1) << 5;
#pragma unroll
      for (int q = 0; q < 4; ++q) {
        float4 a0 = *(const float4*)&T[lj * 68 + cg + (q << 3)];
        float4 a1 = *(const float4*)&T[lj * 68 + cg + (q << 3) + 4];
        short8 o;
        o[0] = (short)bf16rn(a0.x); o[1] = (short)bf16rn(a0.y);
        o[2] = (short)bf16rn(a0.z); o[3] = (short)bf16rn(a0.w);
        o[4] = (short)bf16rn(a1.x); o[5] = (short)bf16rn(a1.y);
        o[6] = (short)bf16rn(a1.z); o[7] = (short)bf16rn(a1.w);
        *(short8*)&A[(size_t)(j0 + lj) * NN + i0 + (c2 << 6) + cg + (q << 3)] = o;
      }
    }
  }
}

// ---------------- sigma[i] = 7th largest of row i (bf16 A) ----------------
__device__ __forceinline__ void ins7(float (&tv)[7], float v) {
  if (v > tv[6]) {
#pragma unroll
    for (int s = 0; s < 7; s++) {
      if (v > tv[s]) { float tmp = tv[s]; tv[s] = v; v = tmp; }
    }
  }
}
__global__ __launch_bounds__(256) void k_top7(const ushortT* __restrict__ A,
                                              float* __restrict__ sig) {
  int w = threadIdx.x >> 6, lane = threadIdx.x & 63;
  int row = (blockIdx.x << 2) + w;
  const ushortT* a = A + (size_t)row * NN;
  float tv[7];
#pragma unroll
  for (int i = 0; i < 7; i++) tv[i] = -1.0f;
#pragma unroll
  for (int k = 0; k < 8; k++) {
    short8 v = *(const short8*)(a + (k << 9) + (lane << 3));
#pragma unroll
    for (int jj = 0; jj < 8; jj++) ins7(tv, bf2f((ushortT)v[jj]));
  }
  int head = 0;
  float seventh = 0.0f;
  for (int r = 0; r < 7; r++) {
    float h = (head < 7) ? tv[head] : -1.0f;
    float m = h;
#pragma unroll
    for (int off = 32; off; off >>= 1) m = fmaxf(m, __shfl_xor(m, off));
    unsigned long long ball = __ballot(h == m);
    if (lane == (__ffsll(ball) - 1)) head++;
    seventh = m;
  }
  if (lane == 0) sig[row] = seventh;
}

// ---------------- mean pass over bf16 A ----------------
__global__ __launch_bounds__(256) void k_transform(const ushortT* __restrict__ A,
                                                   const float* __restrict__ sig,
                                                   double* __restrict__ parts) {
  int row = blockIdx.x;
  float si = sig[row];
  const ushortT* a = A + (size_t)row * NN;
  int t = threadIdx.x;
  double local = 0.0;
#pragma unroll
  for (int k = 0; k < 2; k++) {
    int idx = (k << 11) + (t << 3);
    short8 v = *(const short8*)(a + idx);
#pragma unroll
    for (int q = 0; q < 2; ++q) {
      float4 sg = *(const float4*)&sig[idx + (q << 2)];
      float s0 = bf2f((ushortT)v[(q << 2) + 0]);
      float s1 = bf2f((ushortT)v[(q << 2) + 1]);
      float s2 = bf2f((ushortT)v[(q << 2) + 2]);
      float s3 = bf2f((ushortT)v[(q << 2) + 3]);
      local += (double)expf(-(s0 * s0) / (si * sg.x)) +
               (double)expf(-(s1 * s1) / (si * sg.y)) +
               (double)expf(-(s2 * s2) / (si * sg.z)) +
               (double)expf(-(s3 * s3) / (si * sg.w));
    }
  }
  __shared__ double dred[4];
  int lane = t & 63, wv = t >> 6;
#pragma unroll
  for (int off = 32; off; off >>= 1) local += __shfl_xor(local, off);
  if (lane == 0) dred[wv] = local;
  __syncthreads();
  if (t == 0) parts[row] = dred[0] + dred[1] + dred[2] + dred[3];
}

__global__ __launch_bounds__(256) void k_mean(const double* __restrict__ parts,
                                              float* __restrict__ meanb) {
  int t = threadIdx.x;
  double local = 0.0;
#pragma unroll
  for (int k = 0; k < NN / 256; k++) local += parts[(k << 8) + t];
  __shared__ double dred[4];
  int lane = t & 63, wv = t >> 6;
#pragma unroll
  for (int off = 32; off; off >>= 1) local += __shfl_xor(local, off);
  if (lane == 0) dred[wv] = local;
  __syncthreads();
  if (t == 0) meanb[0] = (float)((dred[0] + dred[1] + dred[2] + dred[3]) / ((double)NN * (double)NN));
}

// ---------------- thresh: exp on bottom half (bf16 A), threshold, pack ----------------
__global__ __launch_bounds__(256) void k_thresh_pack(const ushortT* __restrict__ A,
                                                     const float* __restrict__ sig,
                                                     const float* __restrict__ meanb,
                                                     ushortT* __restrict__ ApL,
                                                     ushortT* __restrict__ ApU) {
  float m = meanb[0];
  int i8 = ((int)blockIdx.x << 8) + threadIdx.x;  // 1M over [2048][512 groups of 8]
  int row2 = i8 >> 9;
  int col8 = (i8 & 511) << 3;
  int grow = NLAB + row2;
  float si = sig[grow];
  short8 v = *(const short8*)&A[(size_t)grow * NN + col8];
  short8 o;
#pragma unroll
  for (int q = 0; q < 2; ++q) {
    float4 sg = *(const float4*)&sig[col8 + (q << 2)];
    float s0 = bf2f((ushortT)v[(q << 2) + 0]);
    float s1 = bf2f((ushortT)v[(q << 2) + 1]);
    float s2 = bf2f((ushortT)v[(q << 2) + 2]);
    float s3 = bf2f((ushortT)v[(q << 2) + 3]);
    float c0 = expf(-(s0 * s0) / (si * sg.x));
    float c1 = expf(-(s1 * s1) / (si * sg.y));
    float c2 = expf(-(s2 * s2) / (si * sg.z));
    float c3 = expf(-(s3 * s3) / (si * sg.w));
    o[(q << 2) + 0] = (short)((c0 < m) ? 0 : bf16rn(c0));
    o[(q << 2) + 1] = (short)((c1 < m) ? 0 : bf16rn(c1));
    o[(q << 2) + 2] = (short)((c2 < m) ? 0 : bf16rn(c2));
    o[(q << 2) + 3] = (short)((c3 < m) ? 0 : bf16rn(c3));
  }
  int half = col8 >> 11;
  int cc = col8 & 2047;
  int rt = row2 >> 4, arow = row2 & 15;
  int kc = cc >> 5, khi = (cc >> 3) & 3;
  ushortT* dst = half ? ApU : ApL;
  *(short8*)&dst[((size_t)((rt << 6) + kc) << 9) + (khi << 7) + (arow << 3)] = o;
}

// ---------------- one-hot labels, packed layout ----------------
__global__ __launch_bounds__(256) void k_xlabp(const int* __restrict__ labels,
                                               ushortT* __restrict__ Xlabp) {
  int idx = ((int)blockIdx.x << 8) + threadIdx.x;  // 262144
  int c = idx >> 11, j = idx & 2047;
  int kc = j >> 5, khi = (j >> 3) & 3, k0 = j & 7;
  int cf = c >> 4, slot = c & 15;
  Xlabp[((size_t)(((kc << 3) + cf) << 2) + khi) * 128 + (slot << 3) + k0] =
      (labels[j] == c) ? (ushortT)0x3F80 : (ushortT)0;
}

// ---------------- X init ----------------
__global__ __launch_bounds__(64) void k_xinit(float* __restrict__ Xf,
                                              ushortT* __restrict__ Xp) {
  int rt = blockIdx.x, l = threadIdx.x;
  int col = l & 15, rg4 = l >> 4;
  int kc = rt >> 1;
  int kk = ((rt & 1) << 4) + (rg4 << 2);
  int khi = kk >> 3, k0 = kk & 7;
#pragma unroll
  for (int cf = 0; cf < 8; ++cf) {
    int cls = (cf << 4) + col;
    float v = (cls < NC) ? 0.01f : 0.0f;
    ((f32x4*)Xf)[(size_t)((rt << 3) + cf) * 64 + l] = (f32x4){v, v, v, v};
    ushortT h = bf16rn(v);
    ushort4 hv = {h, h, h, h};
    *(ushort4*)&Xp[((size_t)(((kc << 3) + cf) << 2) + khi) * 128 + (col << 3) + k0] = hv;
  }
}

// ---------------- Ylab path: partial GEMM + reduce (one-time) ----------------
__global__ __launch_bounds__(256) void k_gP(const ushortT* __restrict__ Ap,
                                            const ushortT* __restrict__ Xp,
                                            float* __restrict__ Pp) {
  int t = threadIdx.x, l = t & 63, w = t >> 6;
  int bid = (int)blockIdx.x;
  int rt = ((bid & 7) << 4) + ((bid >> 3) & 15);
  int s = bid >> 7;  // 0..3
  int kc0 = (s << 4) + (w << 2);
  const ushortT* ab = Ap + ((size_t)rt << 15) + ((size_t)kc0 << 9) + (l << 3);
  const ushortT* xb = Xp + ((size_t)kc0 << 12) + (l << 3);
  short8 av[4];
#pragma unroll
  for (int i = 0; i < 4; ++i) av[i] = *(const short8*)(ab + ((size_t)i << 9));
  f32x4 acc[8];
#pragma unroll
  for (int cf = 0; cf < 8; ++cf) {
    acc[cf] = (f32x4){0.f, 0.f, 0.f, 0.f};
#pragma unroll
    for (int i = 0; i < 4; ++i) {
      short8 bv = *(const short8*)(xb + ((size_t)i << 12) + (cf << 9));
      acc[cf] = __builtin_amdgcn_mfma_f32_16x16x32_bf16(av[i], bv, acc[cf], 0, 0, 0);
    }
  }
  __shared__ float red[4][8][64][4];  // 32 KB
#pragma unroll
  for (int cf = 0; cf < 8; ++cf) *(f32x4*)&red[w][cf][l][0] = acc[cf];
  __syncthreads();
  if (w < 2) {
#pragma unroll
    for (int q = 0; q < 4; ++q) {
      int cf = (w << 2) + q;
      f32x4 sum = *(const f32x4*)&red[0][cf][l][0];
#pragma unroll
      for (int wp = 1; wp < 4; ++wp) {
        f32x4 p = *(const f32x4*)&red[wp][cf][l][0];
        sum[0] += p[0]; sum[1] += p[1]; sum[2] += p[2]; sum[3] += p[3];
      }
      ((f32x4*)Pp)[((size_t)(((s << 7) + rt) << 3) + cf) * 64 + l] = sum;
    }
  }
}

__global__ __launch_bounds__(64) void k_updY(const float* __restrict__ Pp,
                                             float* __restrict__ YlabF) {
  int rt = blockIdx.x, l = threadIdx.x;
#pragma unroll
  for (int cf = 0; cf < 8; ++cf) {
    f32x4 acc = (f32x4){0.f, 0.f, 0.f, 0.f};
#pragma unroll
    for (int s = 0; s < 4; ++s) {
      f32x4 p = ((const f32x4*)Pp)[((size_t)(((s << 7) + rt) << 3) + cf) * 64 + l];
      acc[0] += p[0]; acc[1] += p[1]; acc[2] += p[2]; acc[3] += p[3];
    }
    ((f32x4*)YlabF)[(size_t)((rt << 3) + cf) * 64 + l] = acc;
  }
}

// ---------------- iteration kernel: 256 blocks x 512 thr (8 waves/CU) ----------------
// Block = (rtp: 32 rows) x (q: cf-quarter, 2 cf) x full K.
// Wave w: row-tile h=w>>2, K-quarter kq=w&3. 32 MFMA/wave. LDS K-reduce.
// Rowsum: 4-way same-XCD cross-block exchange, fixed-order read (deterministic).
__global__ __launch_bounds__(512) void k_it3(
    const ushortT* __restrict__ Ap, const ushortT* __restrict__ Xp,
    const float* __restrict__ YlabF, const float* __restrict__ XfPrev,
    float* __restrict__ XfOut, ushortT* __restrict__ XpOut,
    float* __restrict__ sums4, int* __restrict__ cnt4) {
  __shared__ float red[8][2][64][4];  // 16 KB
  __shared__ float sums_l[2][2][16];
  __shared__ float totl[2][16];
  int t = threadIdx.x, l = t & 63, w = t >> 6;
  int bid = (int)blockIdx.x;
  int rtp = ((bid & 7) << 3) + ((bid >> 3) & 7);  // XCD-pinned 32-row groups
  int q = bid >> 6;                               // cf-quarter; partners bid^{64,128,192} same XCD
  int h = w >> 2, kq = w & 3;
  int rt = (rtp << 1) + h;
  int kc0 = kq << 4;
  int rg4 = l >> 4, col16 = l & 15;

  const ushortT* ab = Ap + ((size_t)rt << 15) + ((size_t)kc0 << 9) + (l << 3);
  const ushortT* xb = Xp + ((size_t)kc0 << 12) + ((size_t)(q << 1) << 9) + (l << 3);
  f32x4 acc[2];
  acc[0] = (f32x4){0.f, 0.f, 0.f, 0.f};
  acc[1] = (f32x4){0.f, 0.f, 0.f, 0.f};
#pragma unroll
  for (int i = 0; i < 16; ++i) {
    short8 av = *(const short8*)(ab + ((size_t)i << 9));
#pragma unroll
    for (int cc = 0; cc < 2; ++cc) {
      short8 bv = *(const short8*)(xb + ((size_t)i << 12) + (cc << 9));
      acc[cc] = __builtin_amdgcn_mfma_f32_16x16x32_bf16(av, bv, acc[cc], 0, 0, 0);
    }
  }
  *(f32x4*)&red[w][0][l][0] = acc[0];
  *(f32x4*)&red[w][1][l][0] = acc[1];
  __syncthreads();

  bool owner = ((w & 3) < 2);  // waves 0,1,4,5
  int cc = w & 3;              // valid when owner
  int cf = (q << 1) + cc;
  f32x4 mm = (f32x4){0.f, 0.f, 0.f, 0.f};
  f32x4 mult = mm;
  if (owner) {
#pragma unroll
    for (int k = 0; k < 4; ++k) {
      f32x4 p = *(const f32x4*)&red[(h << 2) + k][cc][l][0];
      mm[0] += p[0]; mm[1] += p[1]; mm[2] += p[2]; mm[3] += p[3];
    }
    size_t fo = (size_t)((rt << 3) + cf) * 64 + l;
    f32x4 yl = ((const f32x4*)YlabF)[fo];
    f32x4 xv = ((const f32x4*)XfPrev)[fo];
    f32x4 rs;
#pragma unroll
    for (int r = 0; r < 4; ++r) {
      mult[r] = fmaf(xv[r], mm[r] + yl[r], xv[r]);
      rs[r] = mult[r];
    }
#pragma unroll
    for (int msk = 1; msk < 16; msk <<= 1) {
#pragma unroll
      for (int r = 0; r < 4; ++r) rs[r] += __shfl_xor(rs[r], msk);
    }
    if (col16 == 0) {
#pragma unroll
      for (int r = 0; r < 4; ++r) sums_l[h][cc][(rg4 << 2) + r] = rs[r];
    }
  }
  __syncthreads();
  // 4-way exchange: waves 0 and 4 publish block partials (32-col sums) to slot q
  if ((w == 0 || w == 4) && l < 16) {
    float bp = sums_l[h][0][l] + sums_l[h][1][l];
    __hip_atomic_exchange(&sums4[((size_t)rt << 6) + (q << 4) + l], bp,
                          __ATOMIC_RELAXED, __HIP_MEMORY_SCOPE_AGENT);
  }
  if ((w == 0 || w == 4) && l == 0) {
    asm volatile("s_waitcnt vmcnt(0)" ::: "memory");
    atomicAdd(&cnt4[rtp], 1);
  }
  if (t == 0) {
    while (atomicAdd(&cnt4[rtp], 0) < 8) __builtin_amdgcn_s_sleep(1);
  }
  __syncthreads();
  if ((w == 0 || w == 4) && l < 16) {
    float s = 1e-8f;
#pragma unroll
    for (int qq = 0; qq < 4; ++qq)
      s += atomicAdd(&sums4[((size_t)rt << 6) + (qq << 4) + l], 0.0f);
    totl[h][l] = s;
  }
  __syncthreads();
  if (owner) {
    f32x4 ov;
#pragma unroll
    for (int r = 0; r < 4; ++r) ov[r] = mult[r] / totl[h][(rg4 << 2) + r];
    size_t fo = (size_t)((rt << 3) + cf) * 64 + l;
    ((f32x4*)XfOut)[fo] = ov;
    int kcp = rt >> 1;
    int rem = ((rt & 1) << 4) + (rg4 << 2);
    int khi = rem >> 3, k0 = rem & 7;
    ushort4 xo;
    xo.x = bf16rn(ov[0]); xo.y = bf16rn(ov[1]);
    xo.z = bf16rn(ov[2]); xo.w = bf16rn(ov[3]);
    *(ushort4*)&XpOut[((size_t)(((kcp << 3) + cf) << 2) + khi) * 128 + (col16 << 3) + k0] = xo;
  }
}

// ---------------- output assembly ----------------
__global__ __launch_bounds__(256) void k_output(const float* __restrict__ Xf,
                                                const int* __restrict__ labels,
                                                float* __restrict__ out) {
  int idx = ((int)blockIdx.x << 8) + threadIdx.x;  // 409600
  int i = idx / NC, c = idx - i * NC;
  float v;
  if (i < NLAB) {
    v = (labels[i] == c) ? 1.0f : 0.0f;
  } else {
    int row = i - NLAB;
    int rt = row >> 4, r = row & 15;
    int rg4 = r >> 2, reg = r & 3;
    int cf = c >> 4, col = c & 15;
    v = Xf[((size_t)(((rt << 3) + cf) << 6) + (rg4 << 4) + col) * 4 + reg];
  }
  out[idx] = v;
}

extern "C" void kernel_launch(void* const* d_in, const int* in_sizes, int n_in,
                              void* d_out, int out_size, void* d_ws, size_t ws_size,
                              hipStream_t stream) {
  const float* E = (const float*)d_in[0];
  const int* labels = (const int*)d_in[1];
  float* out = (float*)d_out;
  char* ws = (char*)d_ws;
  const size_t MB = 1024 * 1024;

  ushortT* A = (ushortT*)ws;                      // 32 MB bf16
  ushortT* Enh = (ushortT*)(ws + 32 * MB);        // 8 MB
  ushortT* ApL = (ushortT*)(ws + 40 * MB);        // 8 MB packed A[:, :2048]
  ushortT* ApU = (ushortT*)(ws + 48 * MB);        // 8 MB packed A[:, 2048:]
  float* sig = (float*)(ws + 56 * MB);
  double* parts = (double*)(ws + 56 * MB + 65536);
  float* meanb = (float*)(ws + 56 * MB + 131072);
  ushortT* Xlabp = (ushortT*)(ws + 57 * MB);      // 0.5 MB packed
  float* YlabF = (float*)(ws + 58 * MB);          // 1 MB frag-major
  float* Xf0 = (float*)(ws + 59 * MB);            // 1 MB
  float* Xf1 = (float*)(ws + 60 * MB);            // 1 MB
  ushortT* Xp0 = (ushortT*)(ws + 61 * MB);        // 0.5 MB
  ushortT* Xp1 = (ushortT*)(ws + 62 * MB);        // 0.5 MB
  float* Pp = (float*)(ws + 64 * MB);             // 4 MB (Ylab one-time)
  float* sums4 = (float*)(ws + 68 * MB);          // 30*128*4*16*4 = 960 KB
  int* cnt4 = (int*)(ws + 69 * MB);               // 30*64*4 = 7.5 KB

  k_normalize<<<NN, 256, 0, stream>>>(E, Enh);
  k_syrk_mfma<<<640, 256, 0, stream>>>(Enh, A);
  k_top7<<<NN / 4, 256, 0, stream>>>(A, sig);
  k_transform<<<NN, 256, 0, stream>>>(A, sig, parts);
  k_mean<<<1, 256, 0, stream>>>(parts, meanb);
  k_thresh_pack<<<4096, 256, 0, stream>>>(A, sig, meanb, ApL, ApU);
  k_xlabp<<<1024, 256, 0, stream>>>(labels, Xlabp);
  k_xinit<<<128, 64, 0, stream>>>(Xf0, Xp0);
  hipMemsetAsync(sums4, 0, (size_t)NITER * 128 * 4 * 16 * sizeof(float), stream);
  hipMemsetAsync(cnt4, 0, (size_t)NITER * 64 * sizeof(int), stream);
  k_gP<<<512, 256, 0, stream>>>(ApL, Xlabp, Pp);
  k_updY<<<128, 64, 0, stream>>>(Pp, YlabF);
  float* xf[2] = {Xf0, Xf1};
  ushortT* xp[2] = {Xp0, Xp1};
  int cur = 0;
  for (int it = 0; it < NITER; ++it) {
    int nxt = cur ^ 1;
    k_it3<<<256, 512, 0, stream>>>(ApU, xp[cur], YlabF, xf[cur], xf[nxt], xp[nxt],
                                   sums4 + (size_t)it * 8192, cnt4 + (size_t)it * 64);
    cur = nxt;
  }
  k_output<<<1600, 256, 0, stream>>>(xf[cur], labels, out);
}